// Round 3
// baseline (548.211 us; speedup 1.0000x reference)
//
#include <hip/hip_runtime.h>
#include <stdint.h>

// dx/dt = F - B*x - r * rowsum(x * (A@x))  broadcast over DIM
// A: 10000x10000 f32 streamed once (400MB -> ~63.5us HBM floor).
// A@x via bf16 MFMA 16x16x32 (absmax 4.0 vs threshold 20.64 — verified R1).
//
// R7: 4KB-burst staging. Evidence ladder: fill (dense adjacent 4KB writes)
// = 6.5 TB/s; R4/R6 (16K streams x 1KB probes) = ~1.7; R5 (80K x 128B)
// = ~1.4. R6 proved counted-vmcnt pipelining is NOT the lever (= R4), so
// the gemm is DRAM-pattern-limited, not latency-limited. Lever: burst
// length. CHUNK_K=1024 -> each row staged as 4 back-to-back 1KB
// global_load_lds (4KB sequential per row-touch), dbuf 2x64KB LDS,
// 1 block/CU (full VGPR file per wave -> all 32 B-frag loads of a chunk
// live in 128 VGPRs, issued BEFORE the stage prefetch so in-order vmcnt
// never drains it: B-issue -> vmcnt(32) -> stage(c+1) -> vmcnt(16) ->
// barrier -> 32 MFMA -> barrier). Max 48 outstanding/wave (<63 HW).
// Predict gemm -> 90-120us, total -> ~390-420us, absmax 4.0 unchanged.

#define N_ROWS 10000
#define DIM 64
#define KTILE 32
#define NKT 320       // K padded to 10240: 320 tiles of 32; B zero-filled past 10000
#define CHUNK_K 1024  // f32 per row per chunk (4KB/row burst)
#define NCHUNK 5      // per K-half: 5*1024 = 5120 cols (32-aligned split)
#define KHALF 5120
#define F_CONST 1.0f
#define B_CONST 0.1f
#define R_CONST 0.01f

#define SACC_OFF_BYTES 1310720  // packed B ends at 320*4*64*16 = 1310720

typedef __attribute__((ext_vector_type(8))) short s16x8;   // 8 bf16 (MFMA A/B frag)
typedef __attribute__((ext_vector_type(4))) float f32x4;   // MFMA C/D frag
typedef __attribute__((ext_vector_type(4))) uint32_t u32x4;

// round-to-nearest f32 -> bf16, packed pair into one u32
__device__ __forceinline__ uint32_t pack_bf16(float a, float b) {
    uint32_t ua = __builtin_bit_cast(uint32_t, a);
    uint32_t ub = __builtin_bit_cast(uint32_t, b);
    ua += 0x7FFFu + ((ua >> 16) & 1u);
    ub += 0x7FFFu + ((ub >> 16) & 1u);
    return (ua >> 16) | (ub & 0xFFFF0000u);
}

__device__ __forceinline__ s16x8 pack_frag(f32x4 lo, f32x4 hi) {
    u32x4 p;
    p.x = pack_bf16(lo.x, lo.y);
    p.y = pack_bf16(lo.z, lo.w);
    p.z = pack_bf16(hi.x, hi.y);
    p.w = pack_bf16(hi.z, hi.w);
    return __builtin_bit_cast(s16x8, p);
}

// Pack x into per-lane-contiguous MFMA B fragments (bf16), zero-padded past K=10000.
// Fragment id = t*4 + c, t in [0,320). Lane L holds B[k=t*32+(L>>4)*8+j][col=c*16+(L&15)].
// Also zeroes the per-row dot accumulator (ws is re-poisoned 0xAA every call).
__global__ __launch_bounds__(256) void pack_x_kernel(const float* __restrict__ x,
                                                     uint32_t* __restrict__ ws,
                                                     float* __restrict__ sacc) {
    int id = blockIdx.x * 256 + threadIdx.x;  // 0 .. 81919
    if (id < N_ROWS) sacc[id] = 0.0f;
    int frag = id >> 6;
    int L = id & 63;
    int t = frag >> 2;
    int c = frag & 3;
    int k0 = t * KTILE + (L >> 4) * 8;
    int col = c * 16 + (L & 15);
    float v[8];
#pragma unroll
    for (int j = 0; j < 8; ++j) {
        int k = k0 + j;
        v[j] = (k < N_ROWS) ? x[k * DIM + col] : 0.0f;
    }
    u32x4 p;
    p.x = pack_bf16(v[0], v[1]);
    p.y = pack_bf16(v[2], v[3]);
    p.z = pack_bf16(v[4], v[5]);
    p.w = pack_bf16(v[6], v[7]);
    ((u32x4*)ws)[id] = p;
}

// blockIdx.x = row tile (16 rows), blockIdx.y = K half (5 chunks of 1024 each).
// Per chunk per wave: 32 B-frag loads (L2-resident ws) into 128 VGPRs,
// vmcnt(32) [stage(c) landed], issue stage(c+1) (16 x 1KB global_load_lds,
// 4 back-to-back per row = 4KB sequential bursts), vmcnt(16) [B landed,
// stage(c+1) stays in flight], s_barrier, 8 tiles x {2 swizzled
// ds_read_b128 -> pack -> 4 MFMA}, s_barrier. No vmcnt(0) in the loop.
__global__ __launch_bounds__(256, 1) void gemm_dot_kernel(
    const float* __restrict__ A, const float* __restrict__ x,
    const uint32_t* __restrict__ ws, float* __restrict__ sacc) {
    // f32 tile [16 rows][1024 k] per buffer, row stride 4KB = 256 16B-units.
    // Swizzle: within each 64-unit (1KB) window, global unit g of row r lands
    // at LDS unit g ^ (r&7) (achieved by pre-swizzling the per-lane global
    // source; global_load_lds's LDS side is linear lane*16). Read applies the
    // same XOR (low-3 bits only, never crosses windows) -> uniform banks.
    __shared__ __align__(16) float lds[2][16 * CHUNK_K];  // 2 x 64KB

    int tid = threadIdx.x;
    int w = tid >> 6;       // wave 0..3
    int L = tid & 63;       // lane
    int quad = L >> 4;      // 0..3
    int m = L & 15;         // A-row-in-tile / B col-in-16
    int rbase = blockIdx.x * 16;
    int half = blockIdx.y;  // 0,1 -> k in [half*5120, half*5120+5120)
    const float* Ab = A + (size_t)rbase * N_ROWS;
    const u32x4* pb = (const u32x4*)ws;

    // Stage chunk c into buffer b: wave w loads rows w*4..w*4+3; per row,
    // 4 consecutive 1KB instructions (windows j=0..3) = one 4KB burst.
    // Clamp keeps tail reads in-bounds (dup data there meets zero B-frags).
    auto stage = [&](int c, int b) {
#pragma unroll
        for (int i = 0; i < 4; ++i) {
            int row = w * 4 + i;
#pragma unroll
            for (int j = 0; j < 4; ++j) {
                int col = half * KHALF + c * CHUNK_K + j * 256 + ((L ^ (row & 7)) << 2);
                if (col > N_ROWS - 4) col = N_ROWS - 4;
                __builtin_amdgcn_global_load_lds(
                    (const __attribute__((address_space(1))) uint32_t*)(Ab + (size_t)row * N_ROWS + col),
                    (__attribute__((address_space(3))) uint32_t*)(&lds[b][row * CHUNK_K + j * 256]),
                    16, 0, 0);
            }
        }
    };

    f32x4 acc[4] = {{0.f, 0.f, 0.f, 0.f},
                    {0.f, 0.f, 0.f, 0.f},
                    {0.f, 0.f, 0.f, 0.f},
                    {0.f, 0.f, 0.f, 0.f}};

    stage(0, 0);
    int p = 0;
    for (int c = 0; c < NCHUNK; ++c) {
        // All 32 B-frag loads for this chunk's 8 tiles FIRST (in-order vmcnt:
        // anything we wait on must be issued before the stage prefetch).
        int T0 = half * (NKT / 2) + c * 32 + w * 8;
        u32x4 bb[32];
#pragma unroll
        for (int u = 0; u < 8; ++u)
#pragma unroll
            for (int cc = 0; cc < 4; ++cc)
                bb[u * 4 + cc] = pb[(size_t)(T0 + u) * 256 + cc * 64 + L];
        __builtin_amdgcn_sched_barrier(0);
        // Outstanding: stage(c) [<=16] + B [32]. Drain to 32 -> stage(c) done.
        asm volatile("s_waitcnt vmcnt(32)" ::: "memory");
        bool more = (c + 1 < NCHUNK);
        if (more) stage(c + 1, p ^ 1);
        __builtin_amdgcn_sched_barrier(0);
        // Outstanding: B [32] + stage(c+1) [16]. Drain to 16 -> B done,
        // prefetch stays in flight. Final iter: nothing to protect.
        if (more) asm volatile("s_waitcnt vmcnt(16)" ::: "memory");
        else      asm volatile("s_waitcnt vmcnt(0)" ::: "memory");
        __builtin_amdgcn_s_barrier();

        // 8 tiles/wave: tt = w*8+u covers chunk-k [tt*32, tt*32+32)
#pragma unroll
        for (int u = 0; u < 8; ++u) {
            int tt = w * 8 + u;
            int g = tt * 8 + quad * 2;  // 16B-unit of k = tt*32 + quad*8
            const char* base = (const char*)&lds[p][0] + m * (CHUNK_K * 4);
            f32x4 lo = *(const f32x4*)(base + ((g ^ (m & 7)) << 4));
            f32x4 hi = *(const f32x4*)(base + (((g + 1) ^ (m & 7)) << 4));
            s16x8 af = pack_frag(lo, hi);
#pragma unroll
            for (int cc = 0; cc < 4; ++cc)
                acc[cc] = __builtin_amdgcn_mfma_f32_16x16x32_bf16(
                    af, __builtin_bit_cast(s16x8, bb[u * 4 + cc]), acc[cc], 0, 0, 0);
        }
        __builtin_amdgcn_s_barrier();  // buf p fully read before next re-stage
        p ^= 1;
    }

    // Per-wave epilogue. C/D layout: acc[cc][r] = Ax_partial[row=quad*4+r][col=cc*16+m].
    float pr[4];
#pragma unroll
    for (int r = 0; r < 4; ++r) {
        int grow = rbase + quad * 4 + r;
        const float* xr = x + (size_t)grow * DIM + m;
        pr[r] = acc[0][r] * xr[0] + acc[1][r] * xr[16] +
                acc[2][r] * xr[32] + acc[3][r] * xr[48];
        pr[r] += __shfl_xor(pr[r], 1);
        pr[r] += __shfl_xor(pr[r], 2);
        pr[r] += __shfl_xor(pr[r], 4);
        pr[r] += __shfl_xor(pr[r], 8);
    }
    if (m == 0) {
#pragma unroll
        for (int r = 0; r < 4; ++r)
            atomicAdd(&sacc[rbase + quad * 4 + r], pr[r]);
    }
}

__global__ __launch_bounds__(256) void finalize_kernel(const float* __restrict__ x,
                                                       const float* __restrict__ sacc,
                                                       float* __restrict__ out) {
    int id = blockIdx.x * 256 + threadIdx.x;  // 0 .. 159999 (f32x4 units)
    f32x4 xv = ((const f32x4*)x)[id];
    float s = R_CONST * sacc[id >> 4];
    f32x4 o;
    o.x = F_CONST - B_CONST * xv.x - s;
    o.y = F_CONST - B_CONST * xv.y - s;
    o.z = F_CONST - B_CONST * xv.z - s;
    o.w = F_CONST - B_CONST * xv.w - s;
    ((f32x4*)out)[id] = o;
}

extern "C" void kernel_launch(void* const* d_in, const int* in_sizes, int n_in,
                              void* d_out, int out_size, void* d_ws, size_t ws_size,
                              hipStream_t stream) {
    // inputs: t (1, unused), x (10000*64 f32), A (10000*10000 f32)
    const float* x = (const float*)d_in[1];
    const float* A = (const float*)d_in[2];
    float* out = (float*)d_out;
    uint32_t* ws = (uint32_t*)d_ws;  // [0, 1.31MB): packed bf16 x fragments (320 tiles)
    float* sacc = (float*)((char*)d_ws + SACC_OFF_BYTES);  // 40KB row-dot acc

    pack_x_kernel<<<320, 256, 0, stream>>>(x, ws, sacc);
    gemm_dot_kernel<<<dim3(625, 2), 256, 0, stream>>>(A, x, ws, sacc);
    finalize_kernel<<<625, 256, 0, stream>>>(x, sacc, out);
}